// Round 23
// baseline (163.674 us; speedup 1.0000x reference)
//
#include <hip/hip_runtime.h>

#define N_NODES 100000
#define N_EDGES 1600000
#define NEG_SLOPE 0.01f
#define NPAD 102400
#define NBLK_SCAN 391   // ceil(100000/256)
#define NPART 16
#define PART_SZ 6250    // 16 * 6250 = 100000 exactly
#define CAPP 110000     // per-partition record capacity
#define BATCH1 1024     // edges per pass-1 block
#define NBLK1 1563      // ceil(1600000/1024)
#define NBLKG 1563      // gemm blocks (ceil(100000/64))
#define DCHUNK 8        // deg-histogram chunks per partition
#define NBLKD (NPART * DCHUNK)  // 128
#define WIN_N 256       // nodes per window
#define NWIN 25         // ceil(6250/256); last window has 106 nodes
#define CAP_B 4608      // per-(partition,window) bucket capacity (mean 4000)
#define NBKT2 (NPART * NWIN)   // 400
#define BATCH1B 1024    // records per pass-1b block
#define NBLK1B 1728     // NPART * ceil(CAPP/1024)
#define CAP_WIN 4608    // staged records in pass2c
#define RCAP 768        // staged records per agg block (mean 256)

// ---- bf16 pack/unpack (RNE) ----
__device__ inline unsigned pk_bf2(float lo, float hi) {
    unsigned a = __builtin_bit_cast(unsigned, lo);
    unsigned b = __builtin_bit_cast(unsigned, hi);
    a = (a + 0x7fffu + ((a >> 16) & 1u)) >> 16;
    b = (b + 0x7fffu + ((b >> 16) & 1u)) >> 16;
    return a | (b << 16);
}
__device__ inline float ub_lo(unsigned u) { return __builtin_bit_cast(float, u << 16); }
__device__ inline float ub_hi(unsigned u) { return __builtin_bit_cast(float, u & 0xffff0000u); }

// ---------------------------------------------------------------------------
// init (blocks 0..399): deg=0, cursors. Block 400: foldw (Wc = W2@Wfc etc).
// ---------------------------------------------------------------------------
__global__ __launch_bounds__(256) void k_init(int* __restrict__ deg,
                                              int* __restrict__ gcur,
                                              int* __restrict__ gcur2,
                                              const float* __restrict__ W2,
                                              const float* __restrict__ b2,
                                              const float* __restrict__ Wfc,
                                              const float* __restrict__ bfc,
                                              float* __restrict__ Wc,
                                              float* __restrict__ cfold) {
    __shared__ float wf[64 * 4];
    const int tid = threadIdx.x;
    if (blockIdx.x < 400) {
        int i = blockIdx.x * 256 + tid;
        if (i < NPAD) deg[i] = 0;
        if (i < NPART) gcur[i] = i * CAPP;
        if (i < NBKT2) gcur2[i] = i * CAP_B;
    } else {
        wf[tid] = Wfc[tid];
        __syncthreads();
        int k = tid >> 2, c = tid & 3;
        float acc = 0.f;
#pragma unroll
        for (int j = 0; j < 64; ++j) acc = fmaf(W2[k * 64 + j], wf[j * 4 + c], acc);
        Wc[k * 4 + c] = acc;
        if (tid < 4) {
            float s = bfc[tid];
            for (int j = 0; j < 64; ++j) s = fmaf(b2[j], wf[j * 4 + tid], s);
            cfold[tid] = s;
        }
    }
}

// ---------------------------------------------------------------------------
// FUSED pass1 + gemm, INTERLEAVED: role = blockIdx&1 (even=pass1, odd=gemm)
// so both workloads co-reside on every CU from t=0 (complementary
// bottlenecks: LDS/atomic vs global-load latency). LDS aliased (32KB).
// ---------------------------------------------------------------------------
__global__ __launch_bounds__(256) void k_p1gemm(const int* __restrict__ src,
                                                const int* __restrict__ dst,
                                                int* __restrict__ gcur,
                                                unsigned* __restrict__ part,
                                                const float* __restrict__ X,
                                                const float* __restrict__ W,
                                                unsigned* __restrict__ Y) {
    __shared__ __align__(16) unsigned smem[8192];   // 32 KiB, aliased
    const int tid = threadIdx.x;
    const int bid = blockIdx.x >> 1;
    if ((blockIdx.x & 1) == 0) {
        // ---------------- pass1 ----------------
        int* hist  = (int*)smem;        // 16
        int* scanb = hist + 16;         // 16
        int* gbase = hist + 32;         // 16
        int* run   = hist + 48;         // 16
        unsigned* stage = smem + 64;    // BATCH1
        const int lane = tid & 63;
        const int e0 = bid * BATCH1;
        if (tid < NPART) hist[tid] = 0;
        __syncthreads();
        unsigned rec[4]; int bk[4], rk[4];
        unsigned long long mm[4];
#pragma unroll
        for (int i = 0; i < 4; ++i) {
            int e = e0 + i * 256 + tid;
            if (e < N_EDGES) {
                int d = dst[e];
                int s = src[e];
                int b = d / PART_SZ;
                bk[i] = b;
                rec[i] = ((unsigned)(d - b * PART_SZ) << 17) | (unsigned)s;
            } else bk[i] = -1;
            unsigned long long m = ~0ULL;
#pragma unroll
            for (int bit = 0; bit < 4; ++bit) {
                unsigned long long vote = __ballot((bk[i] >> bit) & 1);
                m &= ((bk[i] >> bit) & 1) ? vote : ~vote;
            }
            m &= __ballot(bk[i] >= 0);
            mm[i] = m;
            rk[i] = __popcll(m & ((1ULL << lane) - 1ULL));
            if (bk[i] >= 0 && rk[i] == 0)
                atomicAdd(&hist[bk[i]], __popcll(m));   // leader only
        }
        __syncthreads();
        if (tid == 0) {
            int acc = 0;
            for (int b = 0; b < NPART; ++b) { scanb[b] = acc; acc += hist[b]; }
        }
        __syncthreads();
        if (tid < NPART) {
            gbase[tid] = atomicAdd(&gcur[tid], hist[tid]);
            run[tid] = 0;
        }
        __syncthreads();
#pragma unroll
        for (int i = 0; i < 4; ++i) {
            int base_ = 0;
            if (bk[i] >= 0 && rk[i] == 0)
                base_ = atomicAdd(&run[bk[i]], __popcll(mm[i]));   // leader only
            int leader = mm[i] ? (__ffsll((unsigned long long)mm[i]) - 1) : 0;
            base_ = __shfl(base_, leader);
            if (bk[i] >= 0)
                stage[scanb[bk[i]] + base_ + rk[i]] = rec[i];
        }
        __syncthreads();
        for (int b = 0; b < NPART; ++b) {
            int len = hist[b], sb = scanb[b], gb = gbase[b];
            int lim = (b + 1) * CAPP - gb;       // overflow guard
            if (len > lim) len = lim;
            for (int i = tid; i < len; i += 256)
                part[gb + i] = stage[sb + i];
        }
    } else {
        // ---------------- gemm (W in LDS, pipelined broadcast X) -----------
        float* ws = (float*)smem;       // 8192 floats
        const int row0 = bid * 64;
        for (int i = tid; i < 2048; i += 256)
            ((float4*)ws)[i] = ((const float4*)W)[i];
        __syncthreads();
        const int cg = tid & 15, rg = tid >> 4;
        const int c0 = cg * 4;
        const float4* Xv = (const float4*)X;
        size_t rb0, rb1, rb2, rb3;
        {
            int row = row0 + rg * 4;
            rb0 = (size_t)((row     < N_NODES) ? row     : (N_NODES - 1)) * 32;
            rb1 = (size_t)((row + 1 < N_NODES) ? row + 1 : (N_NODES - 1)) * 32;
            rb2 = (size_t)((row + 2 < N_NODES) ? row + 2 : (N_NODES - 1)) * 32;
            rb3 = (size_t)((row + 3 < N_NODES) ? row + 3 : (N_NODES - 1)) * 32;
        }
        float acc[4][4] = {};
        float4 xa0 = Xv[rb0], xa1 = Xv[rb1], xa2 = Xv[rb2], xa3 = Xv[rb3];
#pragma unroll 1
        for (int kq = 0; kq < 32; kq += 2) {
            float4 xb0 = Xv[rb0 + kq + 1], xb1 = Xv[rb1 + kq + 1];
            float4 xb2 = Xv[rb2 + kq + 1], xb3 = Xv[rb3 + kq + 1];
            {
                const int k = kq * 4;
                float4 w0 = *(const float4*)&ws[(k + 0) * 64 + c0];
                float4 w1 = *(const float4*)&ws[(k + 1) * 64 + c0];
                float4 w2 = *(const float4*)&ws[(k + 2) * 64 + c0];
                float4 w3 = *(const float4*)&ws[(k + 3) * 64 + c0];
                float4 xv;
                xv = xa0;
                acc[0][0] = fmaf(xv.x, w0.x, acc[0][0]); acc[0][1] = fmaf(xv.x, w0.y, acc[0][1]);
                acc[0][2] = fmaf(xv.x, w0.z, acc[0][2]); acc[0][3] = fmaf(xv.x, w0.w, acc[0][3]);
                acc[0][0] = fmaf(xv.y, w1.x, acc[0][0]); acc[0][1] = fmaf(xv.y, w1.y, acc[0][1]);
                acc[0][2] = fmaf(xv.y, w1.z, acc[0][2]); acc[0][3] = fmaf(xv.y, w1.w, acc[0][3]);
                acc[0][0] = fmaf(xv.z, w2.x, acc[0][0]); acc[0][1] = fmaf(xv.z, w2.y, acc[0][1]);
                acc[0][2] = fmaf(xv.z, w2.z, acc[0][2]); acc[0][3] = fmaf(xv.z, w2.w, acc[0][3]);
                acc[0][0] = fmaf(xv.w, w3.x, acc[0][0]); acc[0][1] = fmaf(xv.w, w3.y, acc[0][1]);
                acc[0][2] = fmaf(xv.w, w3.z, acc[0][2]); acc[0][3] = fmaf(xv.w, w3.w, acc[0][3]);
                xv = xa1;
                acc[1][0] = fmaf(xv.x, w0.x, acc[1][0]); acc[1][1] = fmaf(xv.x, w0.y, acc[1][1]);
                acc[1][2] = fmaf(xv.x, w0.z, acc[1][2]); acc[1][3] = fmaf(xv.x, w0.w, acc[1][3]);
                acc[1][0] = fmaf(xv.y, w1.x, acc[1][0]); acc[1][1] = fmaf(xv.y, w1.y, acc[1][1]);
                acc[1][2] = fmaf(xv.y, w1.z, acc[1][2]); acc[1][3] = fmaf(xv.y, w1.w, acc[1][3]);
                acc[1][0] = fmaf(xv.z, w2.x, acc[1][0]); acc[1][1] = fmaf(xv.z, w2.y, acc[1][1]);
                acc[1][2] = fmaf(xv.z, w2.z, acc[1][2]); acc[1][3] = fmaf(xv.z, w2.w, acc[1][3]);
                acc[1][0] = fmaf(xv.w, w3.x, acc[1][0]); acc[1][1] = fmaf(xv.w, w3.y, acc[1][1]);
                acc[1][2] = fmaf(xv.w, w3.z, acc[1][2]); acc[1][3] = fmaf(xv.w, w3.w, acc[1][3]);
                xv = xa2;
                acc[2][0] = fmaf(xv.x, w0.x, acc[2][0]); acc[2][1] = fmaf(xv.x, w0.y, acc[2][1]);
                acc[2][2] = fmaf(xv.x, w0.z, acc[2][2]); acc[2][3] = fmaf(xv.x, w0.w, acc[2][3]);
                acc[2][0] = fmaf(xv.y, w1.x, acc[2][0]); acc[2][1] = fmaf(xv.y, w1.y, acc[2][1]);
                acc[2][2] = fmaf(xv.y, w1.z, acc[2][2]); acc[2][3] = fmaf(xv.y, w1.w, acc[2][3]);
                acc[2][0] = fmaf(xv.z, w2.x, acc[2][0]); acc[2][1] = fmaf(xv.z, w2.y, acc[2][1]);
                acc[2][2] = fmaf(xv.z, w2.z, acc[2][2]); acc[2][3] = fmaf(xv.z, w2.w, acc[2][3]);
                acc[2][0] = fmaf(xv.w, w3.x, acc[2][0]); acc[2][1] = fmaf(xv.w, w3.y, acc[2][1]);
                acc[2][2] = fmaf(xv.w, w3.z, acc[2][2]); acc[2][3] = fmaf(xv.w, w3.w, acc[2][3]);
                xv = xa3;
                acc[3][0] = fmaf(xv.x, w0.x, acc[3][0]); acc[3][1] = fmaf(xv.x, w0.y, acc[3][1]);
                acc[3][2] = fmaf(xv.x, w0.z, acc[3][2]); acc[3][3] = fmaf(xv.x, w0.w, acc[3][3]);
                acc[3][0] = fmaf(xv.y, w1.x, acc[3][0]); acc[3][1] = fmaf(xv.y, w1.y, acc[3][1]);
                acc[3][2] = fmaf(xv.y, w1.z, acc[3][2]); acc[3][3] = fmaf(xv.y, w1.w, acc[3][3]);
                acc[3][0] = fmaf(xv.z, w2.x, acc[3][0]); acc[3][1] = fmaf(xv.z, w2.y, acc[3][1]);
                acc[3][2] = fmaf(xv.z, w2.z, acc[3][2]); acc[3][3] = fmaf(xv.z, w2.w, acc[3][3]);
                acc[3][0] = fmaf(xv.w, w3.x, acc[3][0]); acc[3][1] = fmaf(xv.w, w3.y, acc[3][1]);
                acc[3][2] = fmaf(xv.w, w3.z, acc[3][2]); acc[3][3] = fmaf(xv.w, w3.w, acc[3][3]);
            }
            if (kq + 2 < 32) {
                xa0 = Xv[rb0 + kq + 2]; xa1 = Xv[rb1 + kq + 2];
                xa2 = Xv[rb2 + kq + 2]; xa3 = Xv[rb3 + kq + 2];
            }
            {
                const int k = (kq + 1) * 4;
                float4 w0 = *(const float4*)&ws[(k + 0) * 64 + c0];
                float4 w1 = *(const float4*)&ws[(k + 1) * 64 + c0];
                float4 w2 = *(const float4*)&ws[(k + 2) * 64 + c0];
                float4 w3 = *(const float4*)&ws[(k + 3) * 64 + c0];
                float4 xv;
                xv = xb0;
                acc[0][0] = fmaf(xv.x, w0.x, acc[0][0]); acc[0][1] = fmaf(xv.x, w0.y, acc[0][1]);
                acc[0][2] = fmaf(xv.x, w0.z, acc[0][2]); acc[0][3] = fmaf(xv.x, w0.w, acc[0][3]);
                acc[0][0] = fmaf(xv.y, w1.x, acc[0][0]); acc[0][1] = fmaf(xv.y, w1.y, acc[0][1]);
                acc[0][2] = fmaf(xv.y, w1.z, acc[0][2]); acc[0][3] = fmaf(xv.y, w1.w, acc[0][3]);
                acc[0][0] = fmaf(xv.z, w2.x, acc[0][0]); acc[0][1] = fmaf(xv.z, w2.y, acc[0][1]);
                acc[0][2] = fmaf(xv.z, w2.z, acc[0][2]); acc[0][3] = fmaf(xv.z, w2.w, acc[0][3]);
                acc[0][0] = fmaf(xv.w, w3.x, acc[0][0]); acc[0][1] = fmaf(xv.w, w3.y, acc[0][1]);
                acc[0][2] = fmaf(xv.w, w3.z, acc[0][2]); acc[0][3] = fmaf(xv.w, w3.w, acc[0][3]);
                xv = xb1;
                acc[1][0] = fmaf(xv.x, w0.x, acc[1][0]); acc[1][1] = fmaf(xv.x, w0.y, acc[1][1]);
                acc[1][2] = fmaf(xv.x, w0.z, acc[1][2]); acc[1][3] = fmaf(xv.x, w0.w, acc[1][3]);
                acc[1][0] = fmaf(xv.y, w1.x, acc[1][0]); acc[1][1] = fmaf(xv.y, w1.y, acc[1][1]);
                acc[1][2] = fmaf(xv.y, w1.z, acc[1][2]); acc[1][3] = fmaf(xv.y, w1.w, acc[1][3]);
                acc[1][0] = fmaf(xv.z, w2.x, acc[1][0]); acc[1][1] = fmaf(xv.z, w2.y, acc[1][1]);
                acc[1][2] = fmaf(xv.z, w2.z, acc[1][2]); acc[1][3] = fmaf(xv.z, w2.w, acc[1][3]);
                acc[1][0] = fmaf(xv.w, w3.x, acc[1][0]); acc[1][1] = fmaf(xv.w, w3.y, acc[1][1]);
                acc[1][2] = fmaf(xv.w, w3.z, acc[1][2]); acc[1][3] = fmaf(xv.w, w3.w, acc[1][3]);
                xv = xb2;
                acc[2][0] = fmaf(xv.x, w0.x, acc[2][0]); acc[2][1] = fmaf(xv.x, w0.y, acc[2][1]);
                acc[2][2] = fmaf(xv.x, w0.z, acc[2][2]); acc[2][3] = fmaf(xv.x, w0.w, acc[2][3]);
                acc[2][0] = fmaf(xv.y, w1.x, acc[2][0]); acc[2][1] = fmaf(xv.y, w1.y, acc[2][1]);
                acc[2][2] = fmaf(xv.y, w1.z, acc[2][2]); acc[2][3] = fmaf(xv.y, w1.w, acc[2][3]);
                acc[2][0] = fmaf(xv.z, w2.x, acc[2][0]); acc[2][1] = fmaf(xv.z, w2.y, acc[2][1]);
                acc[2][2] = fmaf(xv.z, w2.z, acc[2][2]); acc[2][3] = fmaf(xv.z, w2.w, acc[2][3]);
                acc[2][0] = fmaf(xv.w, w3.x, acc[2][0]); acc[2][1] = fmaf(xv.w, w3.y, acc[2][1]);
                acc[2][2] = fmaf(xv.w, w3.z, acc[2][2]); acc[2][3] = fmaf(xv.w, w3.w, acc[2][3]);
                xv = xb3;
                acc[3][0] = fmaf(xv.x, w0.x, acc[3][0]); acc[3][1] = fmaf(xv.x, w0.y, acc[3][1]);
                acc[3][2] = fmaf(xv.x, w0.z, acc[3][2]); acc[3][3] = fmaf(xv.x, w0.w, acc[3][3]);
                acc[3][0] = fmaf(xv.y, w1.x, acc[3][0]); acc[3][1] = fmaf(xv.y, w1.y, acc[3][1]);
                acc[3][2] = fmaf(xv.y, w1.z, acc[3][2]); acc[3][3] = fmaf(xv.y, w1.w, acc[3][3]);
                acc[3][0] = fmaf(xv.z, w2.x, acc[3][0]); acc[3][1] = fmaf(xv.z, w2.y, acc[3][1]);
                acc[3][2] = fmaf(xv.z, w2.z, acc[3][2]); acc[3][3] = fmaf(xv.z, w2.w, acc[3][3]);
                acc[3][0] = fmaf(xv.w, w3.x, acc[3][0]); acc[3][1] = fmaf(xv.w, w3.y, acc[3][1]);
                acc[3][2] = fmaf(xv.w, w3.z, acc[3][2]); acc[3][3] = fmaf(xv.w, w3.w, acc[3][3]);
            }
        }
#pragma unroll
        for (int j = 0; j < 4; ++j) {
            int row = row0 + rg * 4 + j;
            if (row < N_NODES) {
                uint2 v;
                v.x = pk_bf2(acc[j][0], acc[j][1]);
                v.y = pk_bf2(acc[j][2], acc[j][3]);
                *(uint2*)&Y[(size_t)row * 32 + cg * 2] = v;
            }
        }
    }
}

// ---------------------------------------------------------------------------
// FUSED degh + pass1b. Blocks [0,NBLKD): degree histogram (starts first).
// Blocks [NBLKD, +NBLK1B): re-bin partition records into 25 window-buckets.
// ---------------------------------------------------------------------------
__global__ __launch_bounds__(256) void k_p1bdegh(const unsigned* __restrict__ part,
                                                 const int* __restrict__ gcur,
                                                 int* __restrict__ gcur2,
                                                 unsigned* __restrict__ part2,
                                                 int* __restrict__ deg) {
    __shared__ __align__(16) int smem[PART_SZ];   // 25000 B, aliased
    const int tid = threadIdx.x;
    if (blockIdx.x < NBLKD) {
        // ---------------- degh ----------------
        int* hist = smem;               // PART_SZ
        const int b2 = blockIdx.x;
        const int p = b2 & (NPART - 1);
        const int q = b2 >> 4;          // 0..DCHUNK-1
        const int base = p * CAPP;
        int end = gcur[p]; if (end > base + CAPP) end = base + CAPP;
        const int cnt = end - base;
        const int chunksz = (cnt + DCHUNK - 1) / DCHUNK;
        int rs = base + q * chunksz;
        int re = rs + chunksz; if (re > end) re = end;
        for (int i = tid; i < PART_SZ; i += 256) hist[i] = 0;
        __syncthreads();
        for (int i = rs + tid; i < re; i += 256)
            atomicAdd(&hist[part[i] >> 17], 1);
        __syncthreads();
        const int pbase = p * PART_SZ;
        for (int i = tid; i < PART_SZ; i += 256) {
            int v = hist[i];
            if (v) atomicAdd(&deg[pbase + i], v);
        }
    } else {
        // ---------------- pass1b ----------------
        int* hist  = smem;              // NWIN
        int* scanb = smem + 32;         // NWIN
        int* gbase = smem + 64;         // NWIN
        int* run   = smem + 96;         // NWIN
        unsigned* stage = (unsigned*)(smem + 128);  // BATCH1B
        const int b1b = blockIdx.x - NBLKD;
        const int p = b1b & (NPART - 1);
        const int c = b1b >> 4;
        const int base = p * CAPP;
        int pend = gcur[p]; if (pend > base + CAPP) pend = base + CAPP;
        const int rs = base + c * BATCH1B;
        int re = rs + BATCH1B; if (re > pend) re = pend;
        if (tid < NWIN) { hist[tid] = 0; run[tid] = 0; }
        __syncthreads();
        unsigned rec[4]; int wv[4];
#pragma unroll
        for (int i = 0; i < 4; ++i) {
            int idx = rs + i * 256 + tid;
            if (idx < re) {
                rec[i] = part[idx];
                wv[i] = (int)(rec[i] >> 17) >> 8;   // window 0..24
                atomicAdd(&hist[wv[i]], 1);
            } else wv[i] = -1;
        }
        __syncthreads();
        if (tid == 0) {
            int acc = 0;
            for (int w = 0; w < NWIN; ++w) { scanb[w] = acc; acc += hist[w]; }
        }
        __syncthreads();
        if (tid < NWIN) gbase[tid] = atomicAdd(&gcur2[p * NWIN + tid], hist[tid]);
        __syncthreads();
#pragma unroll
        for (int i = 0; i < 4; ++i) {
            if (wv[i] >= 0) {
                int r = atomicAdd(&run[wv[i]], 1);
                stage[scanb[wv[i]] + r] = rec[i];
            }
        }
        __syncthreads();
        for (int w = 0; w < NWIN; ++w) {
            int len = hist[w], sb = scanb[w], gb = gbase[w];
            int lim = (p * NWIN + w + 1) * CAP_B - gb;   // overflow guard
            if (len > lim) len = lim;
            for (int i = tid; i < len; i += 256)
                part2[gb + i] = stage[sb + i];
        }
    }
}

// ---------------------------------------------------------------------------
// Exclusive scan of in-degree into cur[] + FUSED dinv = rsqrt(deg+1).
// ---------------------------------------------------------------------------
__global__ __launch_bounds__(256) void k_scan1(const int* __restrict__ deg,
                                               int* __restrict__ cur,
                                               int* __restrict__ bsum,
                                               float* __restrict__ dinv) {
    __shared__ int sd[256];
    int t = threadIdx.x;
    int gid = blockIdx.x * 256 + t;
    int v = (gid < N_NODES) ? deg[gid] : 0;
    dinv[gid] = rsqrtf((float)(v + 1));   // +1 self loop
    sd[t] = v;
    __syncthreads();
    for (int off = 1; off < 256; off <<= 1) {
        int add = (t >= off) ? sd[t - off] : 0;
        __syncthreads();
        sd[t] += add;
        __syncthreads();
    }
    cur[gid] = sd[t] - v;  // exclusive
    if (t == 255) bsum[blockIdx.x] = sd[255];
}

__global__ __launch_bounds__(512) void k_scan2(int* __restrict__ bsum) {
    __shared__ int sd[512];
    int t = threadIdx.x;
    int v = (t < NBLK_SCAN) ? bsum[t] : 0;
    sd[t] = v;
    __syncthreads();
    for (int off = 1; off < 512; off <<= 1) {
        int add = (t >= off) ? sd[t - off] : 0;
        __syncthreads();
        sd[t] += add;
        __syncthreads();
    }
    if (t < NBLK_SCAN) bsum[t] = sd[t] - v;  // exclusive
}

__global__ void k_scan3(int* __restrict__ cur, const int* __restrict__ bsum) {
    int gid = blockIdx.x * 256 + threadIdx.x;
    cur[gid] += bsum[blockIdx.x];
}

// ---------------------------------------------------------------------------
// Pass 2c (lite): per-bucket counting sort, sequential burst flush.
// ---------------------------------------------------------------------------
__global__ __launch_bounds__(256) void k_pass2c(const unsigned* __restrict__ part2,
                                                const int* __restrict__ gcur2,
                                                const float* __restrict__ dinv,
                                                const int* __restrict__ cur,
                                                uint2* __restrict__ csr8) {
    __shared__ uint2 stage[CAP_WIN];       // 36 KiB
    __shared__ int lcnt[WIN_N];
    __shared__ int lrun[WIN_N];
    __shared__ int lofs[WIN_N + 1];
    const int g = blockIdx.x;
    const int p = g / NWIN, w = g - p * NWIN;
    const int tid = threadIdx.x;
    const int bs = g * CAP_B;
    int be = gcur2[g]; if (be > bs + CAP_B) be = bs + CAP_B;
    const int dlo = w * WIN_N;
    const int nwin = (PART_SZ - dlo < WIN_N) ? (PART_SZ - dlo) : WIN_N;
    if (tid < WIN_N) { lcnt[tid] = 0; lrun[tid] = 0; }
    __syncthreads();
    for (int i = bs + tid; i < be; i += 256)
        atomicAdd(&lcnt[(int)(part2[i] >> 17) - dlo], 1);
    __syncthreads();
    if (tid == 0) {
        int acc = 0;
        for (int i = 0; i < nwin; ++i) { lofs[i] = acc; acc += lcnt[i]; }
        lofs[nwin] = acc;
    }
    __syncthreads();
    const int pbase = p * PART_SZ;
    const int wbase = cur[pbase + dlo];
    for (int i = bs + tid; i < be; i += 256) {
        unsigned rc = part2[i];
        int dl = (int)(rc >> 17);
        int s = rc & 0x1FFFF;
        int n = pbase + dl;
        float wgt = dinv[s] * dinv[n];
        int pos = lofs[dl - dlo] + atomicAdd(&lrun[dl - dlo], 1);
        uint2 r = make_uint2((unsigned)s, __builtin_bit_cast(unsigned, wgt));
        if (pos < CAP_WIN) stage[pos] = r;
        else csr8[wbase + pos] = r;        // overflow fallback (~never)
    }
    __syncthreads();
    int total = lofs[nwin]; if (total > CAP_WIN) total = CAP_WIN;
    for (int i = tid; i < total; i += 256)
        csr8[wbase + i] = stage[i];        // sequential burst flush
}

// ---------------------------------------------------------------------------
// Layer-1 aggregation, 8-deep gather ILP, dual accumulators.
// ---------------------------------------------------------------------------
__global__ __launch_bounds__(256) void k_agg_bf2(const int* __restrict__ cur,
                                                 const uint2* __restrict__ csr8,
                                                 const float* __restrict__ dinv,
                                                 const unsigned* __restrict__ hb,
                                                 const float* __restrict__ b,
                                                 const float* __restrict__ Wc,
                                                 float* __restrict__ G) {
    __shared__ uint2 rec[RCAP];
    __shared__ int scur[17];
    const int tid = threadIdx.x;
    const int base = blockIdx.x * 16;
    if (tid < 17) scur[tid] = cur[base + tid];
    __syncthreads();
    const int bstart = scur[0];
    const int total = scur[16] - bstart;
    const int staged = (total < RCAP) ? total : RCAP;
    for (int i = tid; i < staged; i += 256) rec[i] = csr8[bstart + i];
    __syncthreads();
    const int lane = tid & 63, wv = tid >> 6;
    const int sub = lane & 31, half = lane >> 5;
    for (int nn = wv; nn < 16; nn += 4) {
        const int node = base + nn;
        const int s = scur[nn], e = scur[nn + 1];
        const float dv = dinv[node];
        float ax = 0.f, ay = 0.f, ax1 = 0.f, ay1 = 0.f;
        if (e - bstart <= staged) {
            int j = s + half, o = j - bstart;
            for (; j + 14 < e; j += 16, o += 16) {
                uint2 r0 = rec[o],      r1 = rec[o + 2],  r2 = rec[o + 4],  r3 = rec[o + 6];
                uint2 r4 = rec[o + 8],  r5 = rec[o + 10], r6 = rec[o + 12], r7 = rec[o + 14];
                unsigned u0 = hb[(size_t)r0.x * 32 + sub];
                unsigned u1 = hb[(size_t)r1.x * 32 + sub];
                unsigned u2 = hb[(size_t)r2.x * 32 + sub];
                unsigned u3 = hb[(size_t)r3.x * 32 + sub];
                unsigned u4 = hb[(size_t)r4.x * 32 + sub];
                unsigned u5 = hb[(size_t)r5.x * 32 + sub];
                unsigned u6 = hb[(size_t)r6.x * 32 + sub];
                unsigned u7 = hb[(size_t)r7.x * 32 + sub];
                float w0 = __builtin_bit_cast(float, r0.y);
                float w1 = __builtin_bit_cast(float, r1.y);
                float w2 = __builtin_bit_cast(float, r2.y);
                float w3 = __builtin_bit_cast(float, r3.y);
                float w4 = __builtin_bit_cast(float, r4.y);
                float w5 = __builtin_bit_cast(float, r5.y);
                float w6 = __builtin_bit_cast(float, r6.y);
                float w7 = __builtin_bit_cast(float, r7.y);
                ax  = fmaf(ub_lo(u0), w0, ax);  ay  = fmaf(ub_hi(u0), w0, ay);
                ax1 = fmaf(ub_lo(u1), w1, ax1); ay1 = fmaf(ub_hi(u1), w1, ay1);
                ax  = fmaf(ub_lo(u2), w2, ax);  ay  = fmaf(ub_hi(u2), w2, ay);
                ax1 = fmaf(ub_lo(u3), w3, ax1); ay1 = fmaf(ub_hi(u3), w3, ay1);
                ax  = fmaf(ub_lo(u4), w4, ax);  ay  = fmaf(ub_hi(u4), w4, ay);
                ax1 = fmaf(ub_lo(u5), w5, ax1); ay1 = fmaf(ub_hi(u5), w5, ay1);
                ax  = fmaf(ub_lo(u6), w6, ax);  ay  = fmaf(ub_hi(u6), w6, ay);
                ax1 = fmaf(ub_lo(u7), w7, ax1); ay1 = fmaf(ub_hi(u7), w7, ay1);
            }
            for (; j + 6 < e; j += 8, o += 8) {
                uint2 r0 = rec[o], r1 = rec[o + 2], r2 = rec[o + 4], r3 = rec[o + 6];
                unsigned u0 = hb[(size_t)r0.x * 32 + sub];
                unsigned u1 = hb[(size_t)r1.x * 32 + sub];
                unsigned u2 = hb[(size_t)r2.x * 32 + sub];
                unsigned u3 = hb[(size_t)r3.x * 32 + sub];
                float w0 = __builtin_bit_cast(float, r0.y);
                float w1 = __builtin_bit_cast(float, r1.y);
                float w2 = __builtin_bit_cast(float, r2.y);
                float w3 = __builtin_bit_cast(float, r3.y);
                ax  = fmaf(ub_lo(u0), w0, ax);  ay  = fmaf(ub_hi(u0), w0, ay);
                ax1 = fmaf(ub_lo(u1), w1, ax1); ay1 = fmaf(ub_hi(u1), w1, ay1);
                ax  = fmaf(ub_lo(u2), w2, ax);  ay  = fmaf(ub_hi(u2), w2, ay);
                ax1 = fmaf(ub_lo(u3), w3, ax1); ay1 = fmaf(ub_hi(u3), w3, ay1);
            }
            for (; j < e; j += 2, o += 2) {
                uint2 r = rec[o];
                float w = __builtin_bit_cast(float, r.y);
                unsigned u = hb[(size_t)r.x * 32 + sub];
                ax = fmaf(ub_lo(u), w, ax); ay = fmaf(ub_hi(u), w, ay);
            }
        } else {  // rare overflow: read records straight from global
            int j = s + half;
            for (; j + 6 < e; j += 8) {
                uint2 r0 = csr8[j], r1 = csr8[j + 2], r2 = csr8[j + 4], r3 = csr8[j + 6];
                unsigned u0 = hb[(size_t)r0.x * 32 + sub];
                unsigned u1 = hb[(size_t)r1.x * 32 + sub];
                unsigned u2 = hb[(size_t)r2.x * 32 + sub];
                unsigned u3 = hb[(size_t)r3.x * 32 + sub];
                ax  = fmaf(ub_lo(u0), __builtin_bit_cast(float, r0.y), ax);
                ay  = fmaf(ub_hi(u0), __builtin_bit_cast(float, r0.y), ay);
                ax1 = fmaf(ub_lo(u1), __builtin_bit_cast(float, r1.y), ax1);
                ay1 = fmaf(ub_hi(u1), __builtin_bit_cast(float, r1.y), ay1);
                ax  = fmaf(ub_lo(u2), __builtin_bit_cast(float, r2.y), ax);
                ay  = fmaf(ub_hi(u2), __builtin_bit_cast(float, r2.y), ay);
                ax1 = fmaf(ub_lo(u3), __builtin_bit_cast(float, r3.y), ax1);
                ay1 = fmaf(ub_hi(u3), __builtin_bit_cast(float, r3.y), ay1);
            }
            for (; j < e; j += 2) {
                uint2 r = csr8[j];
                float w = __builtin_bit_cast(float, r.y);
                unsigned u = hb[(size_t)r.x * 32 + sub];
                ax = fmaf(ub_lo(u), w, ax); ay = fmaf(ub_hi(u), w, ay);
            }
        }
        ax += ax1; ay += ay1;
        ax += __shfl(ax, sub + 32);
        ay += __shfl(ay, sub + 32);
        float g0 = 0.f, g1 = 0.f, g2 = 0.f, g3 = 0.f;
        if (half == 0) {
            unsigned u = hb[(size_t)node * 32 + sub];
            float w = dv * dv;
            float h0 = fmaf(ub_lo(u), w, ax) + b[2 * sub];
            float h1 = fmaf(ub_hi(u), w, ay) + b[2 * sub + 1];
            h0 = (h0 >= 0.f) ? h0 : NEG_SLOPE * h0;
            h1 = (h1 >= 0.f) ? h1 : NEG_SLOPE * h1;
            float4 wc0 = *(const float4*)&Wc[(2 * sub) * 4];
            float4 wc1 = *(const float4*)&Wc[(2 * sub + 1) * 4];
            g0 = fmaf(h0, wc0.x, h1 * wc1.x);
            g1 = fmaf(h0, wc0.y, h1 * wc1.y);
            g2 = fmaf(h0, wc0.z, h1 * wc1.z);
            g3 = fmaf(h0, wc0.w, h1 * wc1.w);
        }
#pragma unroll
        for (int m = 16; m >= 1; m >>= 1) {
            g0 += __shfl_xor(g0, m);
            g1 += __shfl_xor(g1, m);
            g2 += __shfl_xor(g2, m);
            g3 += __shfl_xor(g3, m);
        }
        if (lane == 0)
            *(float4*)&G[(size_t)node * 4] = make_float4(g0, g1, g2, g3);
    }
}

// ---------------------------------------------------------------------------
// 4-wide aggregation (layer 2 folded), 8-deep gather ILP per thread.
// ---------------------------------------------------------------------------
__global__ __launch_bounds__(256) void k_agg4(const int* __restrict__ cur,
                                              const uint2* __restrict__ csr8,
                                              const float* __restrict__ dinv,
                                              const float4* __restrict__ G,
                                              const float* __restrict__ cfold,
                                              float4* __restrict__ out) {
    int node = blockIdx.x * 256 + threadIdx.x;
    if (node >= N_NODES) return;
    int start = cur[node];
    int end = cur[node + 1];
    float dv = dinv[node];
    float4 g = G[node];
    float w0 = dv * dv;
    float4 acc;
    acc.x = fmaf(g.x, w0, cfold[0]);
    acc.y = fmaf(g.y, w0, cfold[1]);
    acc.z = fmaf(g.z, w0, cfold[2]);
    acc.w = fmaf(g.w, w0, cfold[3]);
    int j = start;
    for (; j + 8 <= end; j += 8) {
        uint2 r0 = csr8[j],     r1 = csr8[j + 1], r2 = csr8[j + 2], r3 = csr8[j + 3];
        uint2 r4 = csr8[j + 4], r5 = csr8[j + 5], r6 = csr8[j + 6], r7 = csr8[j + 7];
        float4 g0 = G[r0.x], g1 = G[r1.x], g2 = G[r2.x], g3 = G[r3.x];
        float4 g4 = G[r4.x], g5 = G[r5.x], g6 = G[r6.x], g7 = G[r7.x];
        float a0 = __builtin_bit_cast(float, r0.y);
        float a1 = __builtin_bit_cast(float, r1.y);
        float a2 = __builtin_bit_cast(float, r2.y);
        float a3 = __builtin_bit_cast(float, r3.y);
        float a4 = __builtin_bit_cast(float, r4.y);
        float a5 = __builtin_bit_cast(float, r5.y);
        float a6 = __builtin_bit_cast(float, r6.y);
        float a7 = __builtin_bit_cast(float, r7.y);
        acc.x = fmaf(g0.x, a0, acc.x); acc.y = fmaf(g0.y, a0, acc.y);
        acc.z = fmaf(g0.z, a0, acc.z); acc.w = fmaf(g0.w, a0, acc.w);
        acc.x = fmaf(g1.x, a1, acc.x); acc.y = fmaf(g1.y, a1, acc.y);
        acc.z = fmaf(g1.z, a1, acc.z); acc.w = fmaf(g1.w, a1, acc.w);
        acc.x = fmaf(g2.x, a2, acc.x); acc.y = fmaf(g2.y, a2, acc.y);
        acc.z = fmaf(g2.z, a2, acc.z); acc.w = fmaf(g2.w, a2, acc.w);
        acc.x = fmaf(g3.x, a3, acc.x); acc.y = fmaf(g3.y, a3, acc.y);
        acc.z = fmaf(g3.z, a3, acc.z); acc.w = fmaf(g3.w, a3, acc.w);
        acc.x = fmaf(g4.x, a4, acc.x); acc.y = fmaf(g4.y, a4, acc.y);
        acc.z = fmaf(g4.z, a4, acc.z); acc.w = fmaf(g4.w, a4, acc.w);
        acc.x = fmaf(g5.x, a5, acc.x); acc.y = fmaf(g5.y, a5, acc.y);
        acc.z = fmaf(g5.z, a5, acc.z); acc.w = fmaf(g5.w, a5, acc.w);
        acc.x = fmaf(g6.x, a6, acc.x); acc.y = fmaf(g6.y, a6, acc.y);
        acc.z = fmaf(g6.z, a6, acc.z); acc.w = fmaf(g6.w, a6, acc.w);
        acc.x = fmaf(g7.x, a7, acc.x); acc.y = fmaf(g7.y, a7, acc.y);
        acc.z = fmaf(g7.z, a7, acc.z); acc.w = fmaf(g7.w, a7, acc.w);
    }
    for (; j + 4 <= end; j += 4) {
        uint2 r0 = csr8[j], r1 = csr8[j + 1], r2 = csr8[j + 2], r3 = csr8[j + 3];
        float a0 = __builtin_bit_cast(float, r0.y);
        float a1 = __builtin_bit_cast(float, r1.y);
        float a2 = __builtin_bit_cast(float, r2.y);
        float a3 = __builtin_bit_cast(float, r3.y);
        float4 g0 = G[r0.x], g1 = G[r1.x], g2 = G[r2.x], g3 = G[r3.x];
        acc.x = fmaf(g0.x, a0, acc.x); acc.y = fmaf(g0.y, a0, acc.y);
        acc.z = fmaf(g0.z, a0, acc.z); acc.w = fmaf(g0.w, a0, acc.w);
        acc.x = fmaf(g1.x, a1, acc.x); acc.y = fmaf(g1.y, a1, acc.y);
        acc.z = fmaf(g1.z, a1, acc.z); acc.w = fmaf(g1.w, a1, acc.w);
        acc.x = fmaf(g2.x, a2, acc.x); acc.y = fmaf(g2.y, a2, acc.y);
        acc.z = fmaf(g2.z, a2, acc.z); acc.w = fmaf(g2.w, a2, acc.w);
        acc.x = fmaf(g3.x, a3, acc.x); acc.y = fmaf(g3.y, a3, acc.y);
        acc.z = fmaf(g3.z, a3, acc.z); acc.w = fmaf(g3.w, a3, acc.w);
    }
    for (; j < end; ++j) {
        uint2 r = csr8[j];
        float a = __builtin_bit_cast(float, r.y);
        float4 gs = G[r.x];
        acc.x = fmaf(gs.x, a, acc.x); acc.y = fmaf(gs.y, a, acc.y);
        acc.z = fmaf(gs.z, a, acc.z); acc.w = fmaf(gs.w, a, acc.w);
    }
    out[node] = acc;
}

// ---------------------------------------------------------------------------
extern "C" void kernel_launch(void* const* d_in, const int* in_sizes, int n_in,
                              void* d_out, int out_size, void* d_ws, size_t ws_size,
                              hipStream_t stream) {
    const float* x   = (const float*)d_in[0];
    const int*   ei  = (const int*)d_in[1];
    const float* W1  = (const float*)d_in[2];
    const float* b1  = (const float*)d_in[3];
    const float* W2  = (const float*)d_in[4];
    const float* b2  = (const float*)d_in[5];
    const float* Wfc = (const float*)d_in[6];
    const float* bfc = (const float*)d_in[7];
    float* out = (float*)d_out;

    // workspace layout (4B words)
    int*      deg   = (int*)d_ws;                    // NPAD
    int*      cur   = deg + NPAD;                    // NPAD
    float*    dinv  = (float*)(cur + NPAD);          // NPAD
    int*      bsum  = (int*)(dinv + NPAD);           // 1024
    float*    Wc    = (float*)(bsum + 1024);         // 256
    float*    cfold = Wc + 256;                      // 4 (pad to 256)
    int*      gcur  = (int*)(cfold + 256);           // 16 (pad to 256)
    int*      gcur2 = gcur + 256;                    // 400 (pad to 512)
    unsigned* part  = (unsigned*)(gcur2 + 512);      // NPART*CAPP = 1760000
    unsigned* part2 = part + (size_t)NPART * CAPP;   // NBKT2*CAP_B = 1843200
    uint2*    csr8  = (uint2*)(part2 + (size_t)NBKT2 * CAP_B);  // N_EDGES 8B
    unsigned* hb    = (unsigned*)(csr8 + N_EDGES);   // N*32 packed bf16 pairs
    float*    G     = (float*)(hb + (size_t)N_NODES * 32);      // N*4

    const int* src = ei;
    const int* dst = ei + N_EDGES;

    // init + folded layer-2 weights (block 400)
    k_init<<<401, 256, 0, stream>>>(deg, gcur, gcur2, W2, b2, Wfc, bfc, Wc, cfold);

    // FUSED & INTERLEAVED: pass1 (even blocks) + layer-1 GEMM (odd blocks)
    k_p1gemm<<<NBLK1 + NBLKG, 256, 0, stream>>>(src, dst, gcur, part, x, W1, hb);

    // FUSED: degh (blocks 0..127) + pass1b re-bin (128..1855)
    k_p1bdegh<<<NBLKD + NBLK1B, 256, 0, stream>>>(part, gcur, gcur2, part2, deg);

    // exclusive scan -> per-node start offsets (+ fused dinv)
    k_scan1<<<NBLK_SCAN, 256, 0, stream>>>(deg, cur, bsum, dinv);
    k_scan2<<<1, 512, 0, stream>>>(bsum);
    k_scan3<<<NBLK_SCAN, 256, 0, stream>>>(cur, bsum);

    // pass 2c: per-bucket counting sort, sequential flush
    k_pass2c<<<NBKT2, 256, 0, stream>>>(part2, gcur2, dinv, cur, csr8);

    // ---- layer 1 aggregation: G = leaky(Agg(hb)+b1) @ Wc (fused) ----
    k_agg_bf2<<<N_NODES / 16, 256, 0, stream>>>(cur, csr8, dinv, hb, b1, Wc, G);

    // ---- layer 2 (folded): out = Agg(G) + cfold ----
    k_agg4<<<(N_NODES + 255) / 256, 256, 0, stream>>>(cur, csr8, dinv,
                                                      (const float4*)G, cfold,
                                                      (float4*)out);
}

// Round 24
// 157.687 us; speedup vs baseline: 1.0380x; 1.0380x over previous
//
#include <hip/hip_runtime.h>

#define N_NODES 100000
#define N_EDGES 1600000
#define NEG_SLOPE 0.01f
#define NPAD 102400
#define NBLK_SCAN 391   // ceil(100000/256)
#define NPART 16
#define PART_SZ 6250    // 16 * 6250 = 100000 exactly
#define CAPP 110000     // per-partition record capacity
#define BATCH1 1024     // edges per pass-1 block
#define NBLK1 1563      // ceil(1600000/1024)
#define NBLKG 1563      // gemm blocks (ceil(100000/64))
#define DCHUNK 8        // deg-histogram chunks per partition
#define NBLKD (NPART * DCHUNK)  // 128
#define WIN_N 256       // nodes per window
#define NWIN 25         // ceil(6250/256); last window has 106 nodes
#define CAP_B 4608      // per-(partition,window) bucket capacity (mean 4000)
#define NBKT2 (NPART * NWIN)   // 400
#define BATCH1B 1024    // records per pass-1b block
#define NBLK1B 1728     // NPART * ceil(CAPP/1024)
#define CAP_WIN 4608    // staged records in pass2c
#define RCAP 768        // staged records per agg block (mean 256)

// ---- bf16 pack/unpack (RNE) ----
__device__ inline unsigned pk_bf2(float lo, float hi) {
    unsigned a = __builtin_bit_cast(unsigned, lo);
    unsigned b = __builtin_bit_cast(unsigned, hi);
    a = (a + 0x7fffu + ((a >> 16) & 1u)) >> 16;
    b = (b + 0x7fffu + ((b >> 16) & 1u)) >> 16;
    return a | (b << 16);
}
__device__ inline float ub_lo(unsigned u) { return __builtin_bit_cast(float, u << 16); }
__device__ inline float ub_hi(unsigned u) { return __builtin_bit_cast(float, u & 0xffff0000u); }

// ---------------------------------------------------------------------------
// init (blocks 0..399): deg=0, cursors. Block 400: foldw (Wc = W2@Wfc etc).
// ---------------------------------------------------------------------------
__global__ __launch_bounds__(256) void k_init(int* __restrict__ deg,
                                              int* __restrict__ gcur,
                                              int* __restrict__ gcur2,
                                              const float* __restrict__ W2,
                                              const float* __restrict__ b2,
                                              const float* __restrict__ Wfc,
                                              const float* __restrict__ bfc,
                                              float* __restrict__ Wc,
                                              float* __restrict__ cfold) {
    __shared__ float wf[64 * 4];
    const int tid = threadIdx.x;
    if (blockIdx.x < 400) {
        int i = blockIdx.x * 256 + tid;
        if (i < NPAD) deg[i] = 0;
        if (i < NPART) gcur[i] = i * CAPP;
        if (i < NBKT2) gcur2[i] = i * CAP_B;
    } else {
        wf[tid] = Wfc[tid];
        __syncthreads();
        int k = tid >> 2, c = tid & 3;
        float acc = 0.f;
#pragma unroll
        for (int j = 0; j < 64; ++j) acc = fmaf(W2[k * 64 + j], wf[j * 4 + c], acc);
        Wc[k * 4 + c] = acc;
        if (tid < 4) {
            float s = bfc[tid];
            for (int j = 0; j < 64; ++j) s = fmaf(b2[j], wf[j * 4 + tid], s);
            cfold[tid] = s;
        }
    }
}

// ---------------------------------------------------------------------------
// FUSED pass1 + gemm (block-split layout per R22; interleave regressed).
// Blocks [0,NBLK1): multisplit. Blocks [NBLK1,+NBLKG): hb = bf16(X@W1).
// ---------------------------------------------------------------------------
__global__ __launch_bounds__(256) void k_p1gemm(const int* __restrict__ src,
                                                const int* __restrict__ dst,
                                                int* __restrict__ gcur,
                                                unsigned* __restrict__ part,
                                                const float* __restrict__ X,
                                                const float* __restrict__ W,
                                                unsigned* __restrict__ Y) {
    __shared__ __align__(16) unsigned smem[8192];   // 32 KiB, aliased
    const int tid = threadIdx.x;
    if (blockIdx.x < NBLK1) {
        // ---------------- pass1 ----------------
        int* hist  = (int*)smem;        // 16
        int* scanb = hist + 16;         // 16
        int* gbase = hist + 32;         // 16
        int* run   = hist + 48;         // 16
        unsigned* stage = smem + 64;    // BATCH1
        const int lane = tid & 63;
        const int e0 = blockIdx.x * BATCH1;
        if (tid < NPART) hist[tid] = 0;
        __syncthreads();
        unsigned rec[4]; int bk[4], rk[4];
        unsigned long long mm[4];
#pragma unroll
        for (int i = 0; i < 4; ++i) {
            int e = e0 + i * 256 + tid;
            if (e < N_EDGES) {
                int d = dst[e];
                int s = src[e];
                int b = d / PART_SZ;
                bk[i] = b;
                rec[i] = ((unsigned)(d - b * PART_SZ) << 17) | (unsigned)s;
            } else bk[i] = -1;
            unsigned long long m = ~0ULL;
#pragma unroll
            for (int bit = 0; bit < 4; ++bit) {
                unsigned long long vote = __ballot((bk[i] >> bit) & 1);
                m &= ((bk[i] >> bit) & 1) ? vote : ~vote;
            }
            m &= __ballot(bk[i] >= 0);
            mm[i] = m;
            rk[i] = __popcll(m & ((1ULL << lane) - 1ULL));
            if (bk[i] >= 0 && rk[i] == 0)
                atomicAdd(&hist[bk[i]], __popcll(m));   // leader only
        }
        __syncthreads();
        if (tid == 0) {
            int acc = 0;
            for (int b = 0; b < NPART; ++b) { scanb[b] = acc; acc += hist[b]; }
        }
        __syncthreads();
        if (tid < NPART) {
            gbase[tid] = atomicAdd(&gcur[tid], hist[tid]);
            run[tid] = 0;
        }
        __syncthreads();
#pragma unroll
        for (int i = 0; i < 4; ++i) {
            int base_ = 0;
            if (bk[i] >= 0 && rk[i] == 0)
                base_ = atomicAdd(&run[bk[i]], __popcll(mm[i]));   // leader only
            int leader = mm[i] ? (__ffsll((unsigned long long)mm[i]) - 1) : 0;
            base_ = __shfl(base_, leader);
            if (bk[i] >= 0)
                stage[scanb[bk[i]] + base_ + rk[i]] = rec[i];
        }
        __syncthreads();
        for (int b = 0; b < NPART; ++b) {
            int len = hist[b], sb = scanb[b], gb = gbase[b];
            int lim = (b + 1) * CAPP - gb;       // overflow guard
            if (len > lim) len = lim;
            for (int i = tid; i < len; i += 256)
                part[gb + i] = stage[sb + i];
        }
    } else {
        // ---------------- gemm (W in LDS, pipelined broadcast X) -----------
        float* ws = (float*)smem;       // 8192 floats
        const int row0 = (blockIdx.x - NBLK1) * 64;
        for (int i = tid; i < 2048; i += 256)
            ((float4*)ws)[i] = ((const float4*)W)[i];
        __syncthreads();
        const int cg = tid & 15, rg = tid >> 4;
        const int c0 = cg * 4;
        const float4* Xv = (const float4*)X;
        size_t rb0, rb1, rb2, rb3;
        {
            int row = row0 + rg * 4;
            rb0 = (size_t)((row     < N_NODES) ? row     : (N_NODES - 1)) * 32;
            rb1 = (size_t)((row + 1 < N_NODES) ? row + 1 : (N_NODES - 1)) * 32;
            rb2 = (size_t)((row + 2 < N_NODES) ? row + 2 : (N_NODES - 1)) * 32;
            rb3 = (size_t)((row + 3 < N_NODES) ? row + 3 : (N_NODES - 1)) * 32;
        }
        float acc[4][4] = {};
        float4 xa0 = Xv[rb0], xa1 = Xv[rb1], xa2 = Xv[rb2], xa3 = Xv[rb3];
#pragma unroll 1
        for (int kq = 0; kq < 32; kq += 2) {
            float4 xb0 = Xv[rb0 + kq + 1], xb1 = Xv[rb1 + kq + 1];
            float4 xb2 = Xv[rb2 + kq + 1], xb3 = Xv[rb3 + kq + 1];
            {
                const int k = kq * 4;
                float4 w0 = *(const float4*)&ws[(k + 0) * 64 + c0];
                float4 w1 = *(const float4*)&ws[(k + 1) * 64 + c0];
                float4 w2 = *(const float4*)&ws[(k + 2) * 64 + c0];
                float4 w3 = *(const float4*)&ws[(k + 3) * 64 + c0];
                float4 xv;
                xv = xa0;
                acc[0][0] = fmaf(xv.x, w0.x, acc[0][0]); acc[0][1] = fmaf(xv.x, w0.y, acc[0][1]);
                acc[0][2] = fmaf(xv.x, w0.z, acc[0][2]); acc[0][3] = fmaf(xv.x, w0.w, acc[0][3]);
                acc[0][0] = fmaf(xv.y, w1.x, acc[0][0]); acc[0][1] = fmaf(xv.y, w1.y, acc[0][1]);
                acc[0][2] = fmaf(xv.y, w1.z, acc[0][2]); acc[0][3] = fmaf(xv.y, w1.w, acc[0][3]);
                acc[0][0] = fmaf(xv.z, w2.x, acc[0][0]); acc[0][1] = fmaf(xv.z, w2.y, acc[0][1]);
                acc[0][2] = fmaf(xv.z, w2.z, acc[0][2]); acc[0][3] = fmaf(xv.z, w2.w, acc[0][3]);
                acc[0][0] = fmaf(xv.w, w3.x, acc[0][0]); acc[0][1] = fmaf(xv.w, w3.y, acc[0][1]);
                acc[0][2] = fmaf(xv.w, w3.z, acc[0][2]); acc[0][3] = fmaf(xv.w, w3.w, acc[0][3]);
                xv = xa1;
                acc[1][0] = fmaf(xv.x, w0.x, acc[1][0]); acc[1][1] = fmaf(xv.x, w0.y, acc[1][1]);
                acc[1][2] = fmaf(xv.x, w0.z, acc[1][2]); acc[1][3] = fmaf(xv.x, w0.w, acc[1][3]);
                acc[1][0] = fmaf(xv.y, w1.x, acc[1][0]); acc[1][1] = fmaf(xv.y, w1.y, acc[1][1]);
                acc[1][2] = fmaf(xv.y, w1.z, acc[1][2]); acc[1][3] = fmaf(xv.y, w1.w, acc[1][3]);
                acc[1][0] = fmaf(xv.z, w2.x, acc[1][0]); acc[1][1] = fmaf(xv.z, w2.y, acc[1][1]);
                acc[1][2] = fmaf(xv.z, w2.z, acc[1][2]); acc[1][3] = fmaf(xv.z, w2.w, acc[1][3]);
                acc[1][0] = fmaf(xv.w, w3.x, acc[1][0]); acc[1][1] = fmaf(xv.w, w3.y, acc[1][1]);
                acc[1][2] = fmaf(xv.w, w3.z, acc[1][2]); acc[1][3] = fmaf(xv.w, w3.w, acc[1][3]);
                xv = xa2;
                acc[2][0] = fmaf(xv.x, w0.x, acc[2][0]); acc[2][1] = fmaf(xv.x, w0.y, acc[2][1]);
                acc[2][2] = fmaf(xv.x, w0.z, acc[2][2]); acc[2][3] = fmaf(xv.x, w0.w, acc[2][3]);
                acc[2][0] = fmaf(xv.y, w1.x, acc[2][0]); acc[2][1] = fmaf(xv.y, w1.y, acc[2][1]);
                acc[2][2] = fmaf(xv.y, w1.z, acc[2][2]); acc[2][3] = fmaf(xv.y, w1.w, acc[2][3]);
                acc[2][0] = fmaf(xv.z, w2.x, acc[2][0]); acc[2][1] = fmaf(xv.z, w2.y, acc[2][1]);
                acc[2][2] = fmaf(xv.z, w2.z, acc[2][2]); acc[2][3] = fmaf(xv.z, w2.w, acc[2][3]);
                acc[2][0] = fmaf(xv.w, w3.x, acc[2][0]); acc[2][1] = fmaf(xv.w, w3.y, acc[2][1]);
                acc[2][2] = fmaf(xv.w, w3.z, acc[2][2]); acc[2][3] = fmaf(xv.w, w3.w, acc[2][3]);
                xv = xa3;
                acc[3][0] = fmaf(xv.x, w0.x, acc[3][0]); acc[3][1] = fmaf(xv.x, w0.y, acc[3][1]);
                acc[3][2] = fmaf(xv.x, w0.z, acc[3][2]); acc[3][3] = fmaf(xv.x, w0.w, acc[3][3]);
                acc[3][0] = fmaf(xv.y, w1.x, acc[3][0]); acc[3][1] = fmaf(xv.y, w1.y, acc[3][1]);
                acc[3][2] = fmaf(xv.y, w1.z, acc[3][2]); acc[3][3] = fmaf(xv.y, w1.w, acc[3][3]);
                acc[3][0] = fmaf(xv.z, w2.x, acc[3][0]); acc[3][1] = fmaf(xv.z, w2.y, acc[3][1]);
                acc[3][2] = fmaf(xv.z, w2.z, acc[3][2]); acc[3][3] = fmaf(xv.z, w2.w, acc[3][3]);
                acc[3][0] = fmaf(xv.w, w3.x, acc[3][0]); acc[3][1] = fmaf(xv.w, w3.y, acc[3][1]);
                acc[3][2] = fmaf(xv.w, w3.z, acc[3][2]); acc[3][3] = fmaf(xv.w, w3.w, acc[3][3]);
            }
            if (kq + 2 < 32) {
                xa0 = Xv[rb0 + kq + 2]; xa1 = Xv[rb1 + kq + 2];
                xa2 = Xv[rb2 + kq + 2]; xa3 = Xv[rb3 + kq + 2];
            }
            {
                const int k = (kq + 1) * 4;
                float4 w0 = *(const float4*)&ws[(k + 0) * 64 + c0];
                float4 w1 = *(const float4*)&ws[(k + 1) * 64 + c0];
                float4 w2 = *(const float4*)&ws[(k + 2) * 64 + c0];
                float4 w3 = *(const float4*)&ws[(k + 3) * 64 + c0];
                float4 xv;
                xv = xb0;
                acc[0][0] = fmaf(xv.x, w0.x, acc[0][0]); acc[0][1] = fmaf(xv.x, w0.y, acc[0][1]);
                acc[0][2] = fmaf(xv.x, w0.z, acc[0][2]); acc[0][3] = fmaf(xv.x, w0.w, acc[0][3]);
                acc[0][0] = fmaf(xv.y, w1.x, acc[0][0]); acc[0][1] = fmaf(xv.y, w1.y, acc[0][1]);
                acc[0][2] = fmaf(xv.y, w1.z, acc[0][2]); acc[0][3] = fmaf(xv.y, w1.w, acc[0][3]);
                acc[0][0] = fmaf(xv.z, w2.x, acc[0][0]); acc[0][1] = fmaf(xv.z, w2.y, acc[0][1]);
                acc[0][2] = fmaf(xv.z, w2.z, acc[0][2]); acc[0][3] = fmaf(xv.z, w2.w, acc[0][3]);
                acc[0][0] = fmaf(xv.w, w3.x, acc[0][0]); acc[0][1] = fmaf(xv.w, w3.y, acc[0][1]);
                acc[0][2] = fmaf(xv.w, w3.z, acc[0][2]); acc[0][3] = fmaf(xv.w, w3.w, acc[0][3]);
                xv = xb1;
                acc[1][0] = fmaf(xv.x, w0.x, acc[1][0]); acc[1][1] = fmaf(xv.x, w0.y, acc[1][1]);
                acc[1][2] = fmaf(xv.x, w0.z, acc[1][2]); acc[1][3] = fmaf(xv.x, w0.w, acc[1][3]);
                acc[1][0] = fmaf(xv.y, w1.x, acc[1][0]); acc[1][1] = fmaf(xv.y, w1.y, acc[1][1]);
                acc[1][2] = fmaf(xv.y, w1.z, acc[1][2]); acc[1][3] = fmaf(xv.y, w1.w, acc[1][3]);
                acc[1][0] = fmaf(xv.z, w2.x, acc[1][0]); acc[1][1] = fmaf(xv.z, w2.y, acc[1][1]);
                acc[1][2] = fmaf(xv.z, w2.z, acc[1][2]); acc[1][3] = fmaf(xv.z, w2.w, acc[1][3]);
                acc[1][0] = fmaf(xv.w, w3.x, acc[1][0]); acc[1][1] = fmaf(xv.w, w3.y, acc[1][1]);
                acc[1][2] = fmaf(xv.w, w3.z, acc[1][2]); acc[1][3] = fmaf(xv.w, w3.w, acc[1][3]);
                xv = xb2;
                acc[2][0] = fmaf(xv.x, w0.x, acc[2][0]); acc[2][1] = fmaf(xv.x, w0.y, acc[2][1]);
                acc[2][2] = fmaf(xv.x, w0.z, acc[2][2]); acc[2][3] = fmaf(xv.x, w0.w, acc[2][3]);
                acc[2][0] = fmaf(xv.y, w1.x, acc[2][0]); acc[2][1] = fmaf(xv.y, w1.y, acc[2][1]);
                acc[2][2] = fmaf(xv.y, w1.z, acc[2][2]); acc[2][3] = fmaf(xv.y, w1.w, acc[2][3]);
                acc[2][0] = fmaf(xv.z, w2.x, acc[2][0]); acc[2][1] = fmaf(xv.z, w2.y, acc[2][1]);
                acc[2][2] = fmaf(xv.z, w2.z, acc[2][2]); acc[2][3] = fmaf(xv.z, w2.w, acc[2][3]);
                acc[2][0] = fmaf(xv.w, w3.x, acc[2][0]); acc[2][1] = fmaf(xv.w, w3.y, acc[2][1]);
                acc[2][2] = fmaf(xv.w, w3.z, acc[2][2]); acc[2][3] = fmaf(xv.w, w3.w, acc[2][3]);
                xv = xb3;
                acc[3][0] = fmaf(xv.x, w0.x, acc[3][0]); acc[3][1] = fmaf(xv.x, w0.y, acc[3][1]);
                acc[3][2] = fmaf(xv.x, w0.z, acc[3][2]); acc[3][3] = fmaf(xv.x, w0.w, acc[3][3]);
                acc[3][0] = fmaf(xv.y, w1.x, acc[3][0]); acc[3][1] = fmaf(xv.y, w1.y, acc[3][1]);
                acc[3][2] = fmaf(xv.y, w1.z, acc[3][2]); acc[3][3] = fmaf(xv.y, w1.w, acc[3][3]);
                acc[3][0] = fmaf(xv.z, w2.x, acc[3][0]); acc[3][1] = fmaf(xv.z, w2.y, acc[3][1]);
                acc[3][2] = fmaf(xv.z, w2.z, acc[3][2]); acc[3][3] = fmaf(xv.z, w2.w, acc[3][3]);
                acc[3][0] = fmaf(xv.w, w3.x, acc[3][0]); acc[3][1] = fmaf(xv.w, w3.y, acc[3][1]);
                acc[3][2] = fmaf(xv.w, w3.z, acc[3][2]); acc[3][3] = fmaf(xv.w, w3.w, acc[3][3]);
            }
        }
#pragma unroll
        for (int j = 0; j < 4; ++j) {
            int row = row0 + rg * 4 + j;
            if (row < N_NODES) {
                uint2 v;
                v.x = pk_bf2(acc[j][0], acc[j][1]);
                v.y = pk_bf2(acc[j][2], acc[j][3]);
                *(uint2*)&Y[(size_t)row * 32 + cg * 2] = v;
            }
        }
    }
}

// ---------------------------------------------------------------------------
// FUSED degh + pass1b. Blocks [0,NBLKD): degree histogram (starts first).
// Blocks [NBLKD, +NBLK1B): re-bin partition records into 25 window-buckets.
// ---------------------------------------------------------------------------
__global__ __launch_bounds__(256) void k_p1bdegh(const unsigned* __restrict__ part,
                                                 const int* __restrict__ gcur,
                                                 int* __restrict__ gcur2,
                                                 unsigned* __restrict__ part2,
                                                 int* __restrict__ deg) {
    __shared__ __align__(16) int smem[PART_SZ];   // 25000 B, aliased
    const int tid = threadIdx.x;
    if (blockIdx.x < NBLKD) {
        // ---------------- degh ----------------
        int* hist = smem;               // PART_SZ
        const int b2 = blockIdx.x;
        const int p = b2 & (NPART - 1);
        const int q = b2 >> 4;          // 0..DCHUNK-1
        const int base = p * CAPP;
        int end = gcur[p]; if (end > base + CAPP) end = base + CAPP;
        const int cnt = end - base;
        const int chunksz = (cnt + DCHUNK - 1) / DCHUNK;
        int rs = base + q * chunksz;
        int re = rs + chunksz; if (re > end) re = end;
        for (int i = tid; i < PART_SZ; i += 256) hist[i] = 0;
        __syncthreads();
        for (int i = rs + tid; i < re; i += 256)
            atomicAdd(&hist[part[i] >> 17], 1);
        __syncthreads();
        const int pbase = p * PART_SZ;
        for (int i = tid; i < PART_SZ; i += 256) {
            int v = hist[i];
            if (v) atomicAdd(&deg[pbase + i], v);
        }
    } else {
        // ---------------- pass1b ----------------
        int* hist  = smem;              // NWIN
        int* scanb = smem + 32;         // NWIN
        int* gbase = smem + 64;         // NWIN
        int* run   = smem + 96;         // NWIN
        unsigned* stage = (unsigned*)(smem + 128);  // BATCH1B
        const int b1b = blockIdx.x - NBLKD;
        const int p = b1b & (NPART - 1);
        const int c = b1b >> 4;
        const int base = p * CAPP;
        int pend = gcur[p]; if (pend > base + CAPP) pend = base + CAPP;
        const int rs = base + c * BATCH1B;
        int re = rs + BATCH1B; if (re > pend) re = pend;
        if (tid < NWIN) { hist[tid] = 0; run[tid] = 0; }
        __syncthreads();
        unsigned rec[4]; int wv[4];
#pragma unroll
        for (int i = 0; i < 4; ++i) {
            int idx = rs + i * 256 + tid;
            if (idx < re) {
                rec[i] = part[idx];
                wv[i] = (int)(rec[i] >> 17) >> 8;   // window 0..24
                atomicAdd(&hist[wv[i]], 1);
            } else wv[i] = -1;
        }
        __syncthreads();
        if (tid == 0) {
            int acc = 0;
            for (int w = 0; w < NWIN; ++w) { scanb[w] = acc; acc += hist[w]; }
        }
        __syncthreads();
        if (tid < NWIN) gbase[tid] = atomicAdd(&gcur2[p * NWIN + tid], hist[tid]);
        __syncthreads();
#pragma unroll
        for (int i = 0; i < 4; ++i) {
            if (wv[i] >= 0) {
                int r = atomicAdd(&run[wv[i]], 1);
                stage[scanb[wv[i]] + r] = rec[i];
            }
        }
        __syncthreads();
        for (int w = 0; w < NWIN; ++w) {
            int len = hist[w], sb = scanb[w], gb = gbase[w];
            int lim = (p * NWIN + w + 1) * CAP_B - gb;   // overflow guard
            if (len > lim) len = lim;
            for (int i = tid; i < len; i += 256)
                part2[gb + i] = stage[sb + i];
        }
    }
}

// ---------------------------------------------------------------------------
// Exclusive scan of in-degree into cur[] + FUSED dinv = rsqrt(deg+1).
// ---------------------------------------------------------------------------
__global__ __launch_bounds__(256) void k_scan1(const int* __restrict__ deg,
                                               int* __restrict__ cur,
                                               int* __restrict__ bsum,
                                               float* __restrict__ dinv) {
    __shared__ int sd[256];
    int t = threadIdx.x;
    int gid = blockIdx.x * 256 + t;
    int v = (gid < N_NODES) ? deg[gid] : 0;
    dinv[gid] = rsqrtf((float)(v + 1));   // +1 self loop
    sd[t] = v;
    __syncthreads();
    for (int off = 1; off < 256; off <<= 1) {
        int add = (t >= off) ? sd[t - off] : 0;
        __syncthreads();
        sd[t] += add;
        __syncthreads();
    }
    cur[gid] = sd[t] - v;  // exclusive
    if (t == 255) bsum[blockIdx.x] = sd[255];
}

__global__ __launch_bounds__(512) void k_scan2(int* __restrict__ bsum) {
    __shared__ int sd[512];
    int t = threadIdx.x;
    int v = (t < NBLK_SCAN) ? bsum[t] : 0;
    sd[t] = v;
    __syncthreads();
    for (int off = 1; off < 512; off <<= 1) {
        int add = (t >= off) ? sd[t - off] : 0;
        __syncthreads();
        sd[t] += add;
        __syncthreads();
    }
    if (t < NBLK_SCAN) bsum[t] = sd[t] - v;  // exclusive
}

__global__ void k_scan3(int* __restrict__ cur, const int* __restrict__ bsum) {
    int gid = blockIdx.x * 256 + threadIdx.x;
    cur[gid] += bsum[blockIdx.x];
}

// ---------------------------------------------------------------------------
// Pass 2c (lite): per-bucket counting sort, sequential burst flush.
// ---------------------------------------------------------------------------
__global__ __launch_bounds__(256) void k_pass2c(const unsigned* __restrict__ part2,
                                                const int* __restrict__ gcur2,
                                                const float* __restrict__ dinv,
                                                const int* __restrict__ cur,
                                                uint2* __restrict__ csr8) {
    __shared__ uint2 stage[CAP_WIN];       // 36 KiB
    __shared__ int lcnt[WIN_N];
    __shared__ int lrun[WIN_N];
    __shared__ int lofs[WIN_N + 1];
    const int g = blockIdx.x;
    const int p = g / NWIN, w = g - p * NWIN;
    const int tid = threadIdx.x;
    const int bs = g * CAP_B;
    int be = gcur2[g]; if (be > bs + CAP_B) be = bs + CAP_B;
    const int dlo = w * WIN_N;
    const int nwin = (PART_SZ - dlo < WIN_N) ? (PART_SZ - dlo) : WIN_N;
    if (tid < WIN_N) { lcnt[tid] = 0; lrun[tid] = 0; }
    __syncthreads();
    for (int i = bs + tid; i < be; i += 256)
        atomicAdd(&lcnt[(int)(part2[i] >> 17) - dlo], 1);
    __syncthreads();
    if (tid == 0) {
        int acc = 0;
        for (int i = 0; i < nwin; ++i) { lofs[i] = acc; acc += lcnt[i]; }
        lofs[nwin] = acc;
    }
    __syncthreads();
    const int pbase = p * PART_SZ;
    const int wbase = cur[pbase + dlo];
    for (int i = bs + tid; i < be; i += 256) {
        unsigned rc = part2[i];
        int dl = (int)(rc >> 17);
        int s = rc & 0x1FFFF;
        int n = pbase + dl;
        float wgt = dinv[s] * dinv[n];
        int pos = lofs[dl - dlo] + atomicAdd(&lrun[dl - dlo], 1);
        uint2 r = make_uint2((unsigned)s, __builtin_bit_cast(unsigned, wgt));
        if (pos < CAP_WIN) stage[pos] = r;
        else csr8[wbase + pos] = r;        // overflow fallback (~never)
    }
    __syncthreads();
    int total = lofs[nwin]; if (total > CAP_WIN) total = CAP_WIN;
    for (int i = tid; i < total; i += 256)
        csr8[wbase + i] = stage[i];        // sequential burst flush
}

// ---------------------------------------------------------------------------
// Layer-1 aggregation, 8-deep gather ILP, dual accumulators.
// ---------------------------------------------------------------------------
__global__ __launch_bounds__(256) void k_agg_bf2(const int* __restrict__ cur,
                                                 const uint2* __restrict__ csr8,
                                                 const float* __restrict__ dinv,
                                                 const unsigned* __restrict__ hb,
                                                 const float* __restrict__ b,
                                                 const float* __restrict__ Wc,
                                                 float* __restrict__ G) {
    __shared__ uint2 rec[RCAP];
    __shared__ int scur[17];
    const int tid = threadIdx.x;
    const int base = blockIdx.x * 16;
    if (tid < 17) scur[tid] = cur[base + tid];
    __syncthreads();
    const int bstart = scur[0];
    const int total = scur[16] - bstart;
    const int staged = (total < RCAP) ? total : RCAP;
    for (int i = tid; i < staged; i += 256) rec[i] = csr8[bstart + i];
    __syncthreads();
    const int lane = tid & 63, wv = tid >> 6;
    const int sub = lane & 31, half = lane >> 5;
    for (int nn = wv; nn < 16; nn += 4) {
        const int node = base + nn;
        const int s = scur[nn], e = scur[nn + 1];
        const float dv = dinv[node];
        float ax = 0.f, ay = 0.f, ax1 = 0.f, ay1 = 0.f;
        if (e - bstart <= staged) {
            int j = s + half, o = j - bstart;
            for (; j + 14 < e; j += 16, o += 16) {
                uint2 r0 = rec[o],      r1 = rec[o + 2],  r2 = rec[o + 4],  r3 = rec[o + 6];
                uint2 r4 = rec[o + 8],  r5 = rec[o + 10], r6 = rec[o + 12], r7 = rec[o + 14];
                unsigned u0 = hb[(size_t)r0.x * 32 + sub];
                unsigned u1 = hb[(size_t)r1.x * 32 + sub];
                unsigned u2 = hb[(size_t)r2.x * 32 + sub];
                unsigned u3 = hb[(size_t)r3.x * 32 + sub];
                unsigned u4 = hb[(size_t)r4.x * 32 + sub];
                unsigned u5 = hb[(size_t)r5.x * 32 + sub];
                unsigned u6 = hb[(size_t)r6.x * 32 + sub];
                unsigned u7 = hb[(size_t)r7.x * 32 + sub];
                float w0 = __builtin_bit_cast(float, r0.y);
                float w1 = __builtin_bit_cast(float, r1.y);
                float w2 = __builtin_bit_cast(float, r2.y);
                float w3 = __builtin_bit_cast(float, r3.y);
                float w4 = __builtin_bit_cast(float, r4.y);
                float w5 = __builtin_bit_cast(float, r5.y);
                float w6 = __builtin_bit_cast(float, r6.y);
                float w7 = __builtin_bit_cast(float, r7.y);
                ax  = fmaf(ub_lo(u0), w0, ax);  ay  = fmaf(ub_hi(u0), w0, ay);
                ax1 = fmaf(ub_lo(u1), w1, ax1); ay1 = fmaf(ub_hi(u1), w1, ay1);
                ax  = fmaf(ub_lo(u2), w2, ax);  ay  = fmaf(ub_hi(u2), w2, ay);
                ax1 = fmaf(ub_lo(u3), w3, ax1); ay1 = fmaf(ub_hi(u3), w3, ay1);
                ax  = fmaf(ub_lo(u4), w4, ax);  ay  = fmaf(ub_hi(u4), w4, ay);
                ax1 = fmaf(ub_lo(u5), w5, ax1); ay1 = fmaf(ub_hi(u5), w5, ay1);
                ax  = fmaf(ub_lo(u6), w6, ax);  ay  = fmaf(ub_hi(u6), w6, ay);
                ax1 = fmaf(ub_lo(u7), w7, ax1); ay1 = fmaf(ub_hi(u7), w7, ay1);
            }
            for (; j + 6 < e; j += 8, o += 8) {
                uint2 r0 = rec[o], r1 = rec[o + 2], r2 = rec[o + 4], r3 = rec[o + 6];
                unsigned u0 = hb[(size_t)r0.x * 32 + sub];
                unsigned u1 = hb[(size_t)r1.x * 32 + sub];
                unsigned u2 = hb[(size_t)r2.x * 32 + sub];
                unsigned u3 = hb[(size_t)r3.x * 32 + sub];
                float w0 = __builtin_bit_cast(float, r0.y);
                float w1 = __builtin_bit_cast(float, r1.y);
                float w2 = __builtin_bit_cast(float, r2.y);
                float w3 = __builtin_bit_cast(float, r3.y);
                ax  = fmaf(ub_lo(u0), w0, ax);  ay  = fmaf(ub_hi(u0), w0, ay);
                ax1 = fmaf(ub_lo(u1), w1, ax1); ay1 = fmaf(ub_hi(u1), w1, ay1);
                ax  = fmaf(ub_lo(u2), w2, ax);  ay  = fmaf(ub_hi(u2), w2, ay);
                ax1 = fmaf(ub_lo(u3), w3, ax1); ay1 = fmaf(ub_hi(u3), w3, ay1);
            }
            for (; j < e; j += 2, o += 2) {
                uint2 r = rec[o];
                float w = __builtin_bit_cast(float, r.y);
                unsigned u = hb[(size_t)r.x * 32 + sub];
                ax = fmaf(ub_lo(u), w, ax); ay = fmaf(ub_hi(u), w, ay);
            }
        } else {  // rare overflow: read records straight from global
            int j = s + half;
            for (; j + 6 < e; j += 8) {
                uint2 r0 = csr8[j], r1 = csr8[j + 2], r2 = csr8[j + 4], r3 = csr8[j + 6];
                unsigned u0 = hb[(size_t)r0.x * 32 + sub];
                unsigned u1 = hb[(size_t)r1.x * 32 + sub];
                unsigned u2 = hb[(size_t)r2.x * 32 + sub];
                unsigned u3 = hb[(size_t)r3.x * 32 + sub];
                ax  = fmaf(ub_lo(u0), __builtin_bit_cast(float, r0.y), ax);
                ay  = fmaf(ub_hi(u0), __builtin_bit_cast(float, r0.y), ay);
                ax1 = fmaf(ub_lo(u1), __builtin_bit_cast(float, r1.y), ax1);
                ay1 = fmaf(ub_hi(u1), __builtin_bit_cast(float, r1.y), ay1);
                ax  = fmaf(ub_lo(u2), __builtin_bit_cast(float, r2.y), ax);
                ay  = fmaf(ub_hi(u2), __builtin_bit_cast(float, r2.y), ay);
                ax1 = fmaf(ub_lo(u3), __builtin_bit_cast(float, r3.y), ax1);
                ay1 = fmaf(ub_hi(u3), __builtin_bit_cast(float, r3.y), ay1);
            }
            for (; j < e; j += 2) {
                uint2 r = csr8[j];
                float w = __builtin_bit_cast(float, r.y);
                unsigned u = hb[(size_t)r.x * 32 + sub];
                ax = fmaf(ub_lo(u), w, ax); ay = fmaf(ub_hi(u), w, ay);
            }
        }
        ax += ax1; ay += ay1;
        ax += __shfl(ax, sub + 32);
        ay += __shfl(ay, sub + 32);
        float g0 = 0.f, g1 = 0.f, g2 = 0.f, g3 = 0.f;
        if (half == 0) {
            unsigned u = hb[(size_t)node * 32 + sub];
            float w = dv * dv;
            float h0 = fmaf(ub_lo(u), w, ax) + b[2 * sub];
            float h1 = fmaf(ub_hi(u), w, ay) + b[2 * sub + 1];
            h0 = (h0 >= 0.f) ? h0 : NEG_SLOPE * h0;
            h1 = (h1 >= 0.f) ? h1 : NEG_SLOPE * h1;
            float4 wc0 = *(const float4*)&Wc[(2 * sub) * 4];
            float4 wc1 = *(const float4*)&Wc[(2 * sub + 1) * 4];
            g0 = fmaf(h0, wc0.x, h1 * wc1.x);
            g1 = fmaf(h0, wc0.y, h1 * wc1.y);
            g2 = fmaf(h0, wc0.z, h1 * wc1.z);
            g3 = fmaf(h0, wc0.w, h1 * wc1.w);
        }
#pragma unroll
        for (int m = 16; m >= 1; m >>= 1) {
            g0 += __shfl_xor(g0, m);
            g1 += __shfl_xor(g1, m);
            g2 += __shfl_xor(g2, m);
            g3 += __shfl_xor(g3, m);
        }
        if (lane == 0)
            *(float4*)&G[(size_t)node * 4] = make_float4(g0, g1, g2, g3);
    }
}

// ---------------------------------------------------------------------------
// 4-wide aggregation (layer 2 folded), 8-deep gather ILP per thread.
// ---------------------------------------------------------------------------
__global__ __launch_bounds__(256) void k_agg4(const int* __restrict__ cur,
                                              const uint2* __restrict__ csr8,
                                              const float* __restrict__ dinv,
                                              const float4* __restrict__ G,
                                              const float* __restrict__ cfold,
                                              float4* __restrict__ out) {
    int node = blockIdx.x * 256 + threadIdx.x;
    if (node >= N_NODES) return;
    int start = cur[node];
    int end = cur[node + 1];
    float dv = dinv[node];
    float4 g = G[node];
    float w0 = dv * dv;
    float4 acc;
    acc.x = fmaf(g.x, w0, cfold[0]);
    acc.y = fmaf(g.y, w0, cfold[1]);
    acc.z = fmaf(g.z, w0, cfold[2]);
    acc.w = fmaf(g.w, w0, cfold[3]);
    int j = start;
    for (; j + 8 <= end; j += 8) {
        uint2 r0 = csr8[j],     r1 = csr8[j + 1], r2 = csr8[j + 2], r3 = csr8[j + 3];
        uint2 r4 = csr8[j + 4], r5 = csr8[j + 5], r6 = csr8[j + 6], r7 = csr8[j + 7];
        float4 g0 = G[r0.x], g1 = G[r1.x], g2 = G[r2.x], g3 = G[r3.x];
        float4 g4 = G[r4.x], g5 = G[r5.x], g6 = G[r6.x], g7 = G[r7.x];
        float a0 = __builtin_bit_cast(float, r0.y);
        float a1 = __builtin_bit_cast(float, r1.y);
        float a2 = __builtin_bit_cast(float, r2.y);
        float a3 = __builtin_bit_cast(float, r3.y);
        float a4 = __builtin_bit_cast(float, r4.y);
        float a5 = __builtin_bit_cast(float, r5.y);
        float a6 = __builtin_bit_cast(float, r6.y);
        float a7 = __builtin_bit_cast(float, r7.y);
        acc.x = fmaf(g0.x, a0, acc.x); acc.y = fmaf(g0.y, a0, acc.y);
        acc.z = fmaf(g0.z, a0, acc.z); acc.w = fmaf(g0.w, a0, acc.w);
        acc.x = fmaf(g1.x, a1, acc.x); acc.y = fmaf(g1.y, a1, acc.y);
        acc.z = fmaf(g1.z, a1, acc.z); acc.w = fmaf(g1.w, a1, acc.w);
        acc.x = fmaf(g2.x, a2, acc.x); acc.y = fmaf(g2.y, a2, acc.y);
        acc.z = fmaf(g2.z, a2, acc.z); acc.w = fmaf(g2.w, a2, acc.w);
        acc.x = fmaf(g3.x, a3, acc.x); acc.y = fmaf(g3.y, a3, acc.y);
        acc.z = fmaf(g3.z, a3, acc.z); acc.w = fmaf(g3.w, a3, acc.w);
        acc.x = fmaf(g4.x, a4, acc.x); acc.y = fmaf(g4.y, a4, acc.y);
        acc.z = fmaf(g4.z, a4, acc.z); acc.w = fmaf(g4.w, a4, acc.w);
        acc.x = fmaf(g5.x, a5, acc.x); acc.y = fmaf(g5.y, a5, acc.y);
        acc.z = fmaf(g5.z, a5, acc.z); acc.w = fmaf(g5.w, a5, acc.w);
        acc.x = fmaf(g6.x, a6, acc.x); acc.y = fmaf(g6.y, a6, acc.y);
        acc.z = fmaf(g6.z, a6, acc.z); acc.w = fmaf(g6.w, a6, acc.w);
        acc.x = fmaf(g7.x, a7, acc.x); acc.y = fmaf(g7.y, a7, acc.y);
        acc.z = fmaf(g7.z, a7, acc.z); acc.w = fmaf(g7.w, a7, acc.w);
    }
    for (; j + 4 <= end; j += 4) {
        uint2 r0 = csr8[j], r1 = csr8[j + 1], r2 = csr8[j + 2], r3 = csr8[j + 3];
        float a0 = __builtin_bit_cast(float, r0.y);
        float a1 = __builtin_bit_cast(float, r1.y);
        float a2 = __builtin_bit_cast(float, r2.y);
        float a3 = __builtin_bit_cast(float, r3.y);
        float4 g0 = G[r0.x], g1 = G[r1.x], g2 = G[r2.x], g3 = G[r3.x];
        acc.x = fmaf(g0.x, a0, acc.x); acc.y = fmaf(g0.y, a0, acc.y);
        acc.z = fmaf(g0.z, a0, acc.z); acc.w = fmaf(g0.w, a0, acc.w);
        acc.x = fmaf(g1.x, a1, acc.x); acc.y = fmaf(g1.y, a1, acc.y);
        acc.z = fmaf(g1.z, a1, acc.z); acc.w = fmaf(g1.w, a1, acc.w);
        acc.x = fmaf(g2.x, a2, acc.x); acc.y = fmaf(g2.y, a2, acc.y);
        acc.z = fmaf(g2.z, a2, acc.z); acc.w = fmaf(g2.w, a2, acc.w);
        acc.x = fmaf(g3.x, a3, acc.x); acc.y = fmaf(g3.y, a3, acc.y);
        acc.z = fmaf(g3.z, a3, acc.z); acc.w = fmaf(g3.w, a3, acc.w);
    }
    for (; j < end; ++j) {
        uint2 r = csr8[j];
        float a = __builtin_bit_cast(float, r.y);
        float4 gs = G[r.x];
        acc.x = fmaf(gs.x, a, acc.x); acc.y = fmaf(gs.y, a, acc.y);
        acc.z = fmaf(gs.z, a, acc.z); acc.w = fmaf(gs.w, a, acc.w);
    }
    out[node] = acc;
}

// ---------------------------------------------------------------------------
extern "C" void kernel_launch(void* const* d_in, const int* in_sizes, int n_in,
                              void* d_out, int out_size, void* d_ws, size_t ws_size,
                              hipStream_t stream) {
    const float* x   = (const float*)d_in[0];
    const int*   ei  = (const int*)d_in[1];
    const float* W1  = (const float*)d_in[2];
    const float* b1  = (const float*)d_in[3];
    const float* W2  = (const float*)d_in[4];
    const float* b2  = (const float*)d_in[5];
    const float* Wfc = (const float*)d_in[6];
    const float* bfc = (const float*)d_in[7];
    float* out = (float*)d_out;

    // workspace layout (4B words)
    int*      deg   = (int*)d_ws;                    // NPAD
    int*      cur   = deg + NPAD;                    // NPAD
    float*    dinv  = (float*)(cur + NPAD);          // NPAD
    int*      bsum  = (int*)(dinv + NPAD);           // 1024
    float*    Wc    = (float*)(bsum + 1024);         // 256
    float*    cfold = Wc + 256;                      // 4 (pad to 256)
    int*      gcur  = (int*)(cfold + 256);           // 16 (pad to 256)
    int*      gcur2 = gcur + 256;                    // 400 (pad to 512)
    unsigned* part  = (unsigned*)(gcur2 + 512);      // NPART*CAPP = 1760000
    unsigned* part2 = part + (size_t)NPART * CAPP;   // NBKT2*CAP_B = 1843200
    uint2*    csr8  = (uint2*)(part2 + (size_t)NBKT2 * CAP_B);  // N_EDGES 8B
    unsigned* hb    = (unsigned*)(csr8 + N_EDGES);   // N*32 packed bf16 pairs
    float*    G     = (float*)(hb + (size_t)N_NODES * 32);      // N*4

    const int* src = ei;
    const int* dst = ei + N_EDGES;

    // init + folded layer-2 weights (block 400)
    k_init<<<401, 256, 0, stream>>>(deg, gcur, gcur2, W2, b2, Wfc, bfc, Wc, cfold);

    // FUSED: multisplit pass1 (blocks 0..1562) + layer-1 GEMM (1563..3125)
    k_p1gemm<<<NBLK1 + NBLKG, 256, 0, stream>>>(src, dst, gcur, part, x, W1, hb);

    // FUSED: degh (blocks 0..127) + pass1b re-bin (128..1855)
    k_p1bdegh<<<NBLKD + NBLK1B, 256, 0, stream>>>(part, gcur, gcur2, part2, deg);

    // exclusive scan -> per-node start offsets (+ fused dinv)
    k_scan1<<<NBLK_SCAN, 256, 0, stream>>>(deg, cur, bsum, dinv);
    k_scan2<<<1, 512, 0, stream>>>(bsum);
    k_scan3<<<NBLK_SCAN, 256, 0, stream>>>(cur, bsum);

    // pass 2c: per-bucket counting sort, sequential flush
    k_pass2c<<<NBKT2, 256, 0, stream>>>(part2, gcur2, dinv, cur, csr8);

    // ---- layer 1 aggregation: G = leaky(Agg(hb)+b1) @ Wc (fused) ----
    k_agg_bf2<<<N_NODES / 16, 256, 0, stream>>>(cur, csr8, dinv, hb, b1, Wc, G);

    // ---- layer 2 (folded): out = Agg(G) + cfold ----
    k_agg4<<<(N_NODES + 255) / 256, 256, 0, stream>>>(cur, csr8, dinv,
                                                      (const float4*)G, cfold,
                                                      (float4*)out);
}